// Round 24
// baseline (175.380 us; speedup 1.0000x reference)
//
#include <hip/hip_runtime.h>
#include <math.h>

// Damping: B=32768, N=64, H=256, OFF=2016
//   diag: x -> tanh(Wd1) -> tanh(Wd2) -> Wdo   (64 per sample)
//   off : x -> tanh(Wo1) -> tanh(Wo2) -> Woo   (2016 per sample, strict lower tri)
//   out = L (L^T x0), L diag = xd, L[i][j](j<i) = z[i(i-1)/2+j]
//
// z path v8: 4 XCD-matched slices; gemm_z writes z slice (cached, per-XCD L2),
// apply (XCD-matched sample remap) reads it back from L2.

#define B_TOT 32768
#define NDIM  64
#define HDIM  256
#define OFFD  2016
#define ZCOLS 2048                 // padded row length (bf16)
#define ZROWB 4096                 // bytes per z row

typedef __bf16 bf16x8 __attribute__((ext_vector_type(8)));
typedef float  f32x4  __attribute__((ext_vector_type(4)));
typedef unsigned u32x4 __attribute__((ext_vector_type(4)));

__device__ __forceinline__ float fast_tanh(float x) {
  float e = __expf(2.f * x);
  return 1.f - 2.f * __builtin_amdgcn_rcpf(e + 1.f);
}
__device__ __forceinline__ float lane_bcast(float v, int l) {
  return __uint_as_float(__builtin_amdgcn_readlane(__float_as_uint(v), l));
}
__device__ __forceinline__ float bf_lo(unsigned w) { return __uint_as_float(w << 16); }
__device__ __forceinline__ float bf_hi(unsigned w) { return __uint_as_float(w & 0xffff0000u); }
__device__ __forceinline__ unsigned long long bfb64(float a, float b, float c, float d) {
  __bf16 ha = (__bf16)a, hb = (__bf16)b, hc = (__bf16)c, hd = (__bf16)d;
  return (unsigned long long)__builtin_bit_cast(unsigned short, ha) |
         ((unsigned long long)__builtin_bit_cast(unsigned short, hb) << 16) |
         ((unsigned long long)__builtin_bit_cast(unsigned short, hc) << 32) |
         ((unsigned long long)__builtin_bit_cast(unsigned short, hd) << 48);
}

__device__ __forceinline__ void gload_lds16(const void* g, void* l) {
  __builtin_amdgcn_global_load_lds(
      (const __attribute__((address_space(1))) unsigned*)g,
      (__attribute__((address_space(3))) unsigned*)l, 16, 0, 0);
}

#define MFMA(A, B, C) __builtin_amdgcn_mfma_f32_16x16x32_bf16((A), (B), (C), 0, 0, 0)
#define SB0() __builtin_amdgcn_sched_barrier(0)
// XOR-swizzled 16B-granule byte offset within a row (low 3 bits of granule)
#define GOFF(g, row) (((((g) & ~7) | (((g) & 7) ^ ((row) & 7)))) << 4)

// ---------------- weight cast (f32 -> bf16) + Woob pad zero-fill ----------------
__device__ __forceinline__ void cast_range(const float* __restrict__ s,
                                           __bf16* __restrict__ d, int n) {
  int i = blockIdx.x * blockDim.x + threadIdx.x;
  const int stride = gridDim.x * blockDim.x;
  for (; i < n; i += stride) d[i] = (__bf16)s[i];
}
__global__ __launch_bounds__(256) void cast_all_kernel(
    const float* s0, __bf16* d0, int n0, const float* s1, __bf16* d1, int n1,
    const float* s2, __bf16* d2, int n2, const float* s3, __bf16* d3, int n3,
    const float* s4, __bf16* d4, int n4, const float* s5, __bf16* d5, int n5,
    __bf16* d6, int n6) {
  cast_range(s0, d0, n0); cast_range(s1, d1, n1); cast_range(s2, d2, n2);
  cast_range(s3, d3, n3); cast_range(s4, d4, n4); cast_range(s5, d5, n5);
  int i = blockIdx.x * blockDim.x + threadIdx.x;
  const int stride = gridDim.x * blockDim.x;
  for (; i < n6; i += stride) d6[i] = (__bf16)0.f;
}

__device__ __forceinline__ bf16x8 cvt8(const float* __restrict__ p) {
  const float4 u = *(const float4*)p;
  const float4 v = *(const float4*)(p + 4);
  bf16x8 r;
  r[0] = (__bf16)u.x; r[1] = (__bf16)u.y; r[2] = (__bf16)u.z; r[3] = (__bf16)u.w;
  r[4] = (__bf16)v.x; r[5] = (__bf16)v.y; r[6] = (__bf16)v.z; r[7] = (__bf16)v.w;
  return r;
}

// ---------------- shared trunk machinery: 64 samples/WG, 72KB LDS, 2 WG/CU ------
#define TRK_SMEM (8192 + 32768 + 32768)

// stage one 16KB weight chunk; rows are 128B if c<2 else 512B
__device__ __forceinline__ void stage_chunk2(const char* wreg, char* wb,
                                             int c, int wave) {
  const char* base = wreg + (size_t)c * 16384;
  char* dst = wb + (c & 1) * 16384;
  const int lane = threadIdx.x & 63;
  const int s0 = wave * 64 + lane;
  const int s1 = s0 + 512;
  if (c < 2) {  // 128-byte rows (8 granules)
    const int r0 = s0 >> 3, q0 = (s0 & 7) ^ (r0 & 7);
    gload_lds16(base + r0 * 128 + (q0 << 4), dst + wave * 1024);
    const int r1 = s1 >> 3, q1 = (s1 & 7) ^ (r1 & 7);
    gload_lds16(base + r1 * 128 + (q1 << 4), dst + (wave + 8) * 1024);
  } else {      // 512-byte rows (32 granules)
    const int r0 = s0 >> 5, g0 = s0 & 31;
    const int q0 = (g0 & 24) | ((g0 & 7) ^ (r0 & 7));
    gload_lds16(base + r0 * 512 + (q0 << 4), dst + wave * 1024);
    const int r1 = s1 >> 5, g1 = s1 & 31;
    const int q1 = (g1 & 24) | ((g1 & 7) ^ (r1 & 7));
    gload_lds16(base + r1 * 512 + (q1 << 4), dst + (wave + 8) * 1024);
  }
}

// ---------------- off_trunk: x -> tanh(Wo1) -> tanh(Wo2) -> g2 ------------------
__global__ __launch_bounds__(512, 2) void off_trunk_kernel(
    const float* __restrict__ x, const __bf16* __restrict__ Wreg,
    const float* __restrict__ bo1, const float* __restrict__ bo2,
    __bf16* __restrict__ g2) {
  extern __shared__ char smem[];
  char* xa  = smem;            // 8 KB
  char* act = smem + 8192;     // 32 KB (g1)
  char* wb  = smem + 40960;    // 32 KB
  const char* Wc = (const char*)Wreg;

  const int tid = threadIdx.x;
  const int wave = tid >> 6, lane = tid & 63;
  const int lr = lane & 15, lg = lane >> 4;
  const int sb = blockIdx.x * 64;

  float bv1[2], bv2[8];
#pragma unroll
  for (int cc = 0; cc < 2; ++cc) bv1[cc] = bo1[cc * 128 + wave * 16 + lr];
#pragma unroll
  for (int cc = 0; cc < 8; ++cc) bv2[cc] = bo2[cc * 32 + (wave & 1) * 16 + lr];

  {
    const int s = tid >> 3, g = tid & 7;
    const bf16x8 v = cvt8(x + (size_t)(sb + s) * 64 + g * 8);
    *(bf16x8*)(xa + s * 128 + GOFF(g, s)) = v;
  }
  stage_chunk2(Wc, wb, 0, wave);
  __syncthreads();

#pragma unroll
  for (int cc = 0; cc < 2; ++cc) {
    stage_chunk2(Wc, wb, cc + 1, wave);
    const char* wbp = wb + (cc & 1) * 16384;
    const int brow = wave * 16 + lr;
    const bf16x8 b0 = *(const bf16x8*)(wbp + brow * 128 + GOFF(lg, brow));
    const bf16x8 b1 = *(const bf16x8*)(wbp + brow * 128 + GOFF(4 + lg, brow));
    const int ch = cc * 128 + brow;
#pragma unroll
    for (int m = 0; m < 4; ++m) {
      const int arow = m * 16 + lr;
      const bf16x8 a0 = *(const bf16x8*)(xa + arow * 128 + GOFF(lg, arow));
      const bf16x8 a1 = *(const bf16x8*)(xa + arow * 128 + GOFF(4 + lg, arow));
      f32x4 acc = {0.f, 0.f, 0.f, 0.f};
      acc = MFMA(a0, b0, acc);
      acc = MFMA(a1, b1, acc);
#pragma unroll
      for (int r = 0; r < 4; ++r) {
        const int s = m * 16 + lg * 4 + r;
        *(__bf16*)(act + s * 512 + GOFF(ch >> 3, s) + (ch & 7) * 2) =
            (__bf16)fast_tanh(acc[r] + bv1[cc]);
      }
    }
    __syncthreads();
  }

#pragma unroll
  for (int cc = 0; cc < 8; ++cc) {
    const int c = cc + 2;
    if (c + 1 < 10) stage_chunk2(Wc, wb, c + 1, wave);
    const char* wbp = wb + (c & 1) * 16384;
    const int m = wave >> 1, n = wave & 1;
    const int ch = cc * 32 + n * 16 + lr;
    const int brow = n * 16 + lr;
    const int arow = m * 16 + lr;
    f32x4 acc = {0.f, 0.f, 0.f, 0.f};
#pragma unroll
    for (int ks = 0; ks < 8; ++ks) {
      const int g = ks * 4 + lg;
      const bf16x8 a = *(const bf16x8*)(act + arow * 512 + GOFF(g, arow));
      const bf16x8 b = *(const bf16x8*)(wbp + brow * 512 + GOFF(g, brow));
      acc = MFMA(a, b, acc);
    }
#pragma unroll
    for (int r = 0; r < 4; ++r) {
      const int s = m * 16 + lg * 4 + r;
      g2[(size_t)(sb + s) * 256 + ch] = (__bf16)fast_tanh(acc[r] + bv2[cc]);
    }
    if (cc < 7) __syncthreads();
  }
}

// ---------------- diag_trunk: x -> tanh(Wd1) -> tanh(Wd2) -> Wdo -> xd ----------
__global__ __launch_bounds__(512, 2) void diag_trunk_kernel(
    const float* __restrict__ x, const __bf16* __restrict__ Wreg,
    const float* __restrict__ bd1, const float* __restrict__ bd2,
    const float* __restrict__ bdo, float* __restrict__ xd) {
  extern __shared__ char smem[];
  char* xa  = smem;            // 8 KB
  char* act = smem + 8192;     // 32 KB (h1, then h2)
  char* wb  = smem + 40960;    // 32 KB
  const char* Wc = (const char*)Wreg;

  const int tid = threadIdx.x;
  const int wave = tid >> 6, lane = tid & 63;
  const int lr = lane & 15, lg = lane >> 4;
  const int sb = blockIdx.x * 64;

  float bv1[2], bv2[8], bv3[2];
#pragma unroll
  for (int cc = 0; cc < 2; ++cc) bv1[cc] = bd1[cc * 128 + wave * 16 + lr];
#pragma unroll
  for (int cc = 0; cc < 8; ++cc) bv2[cc] = bd2[cc * 32 + (wave & 1) * 16 + lr];
#pragma unroll
  for (int cc = 0; cc < 2; ++cc) bv3[cc] = bdo[cc * 32 + (wave & 1) * 16 + lr];

  {
    const int s = tid >> 3, g = tid & 7;
    const bf16x8 v = cvt8(x + (size_t)(sb + s) * 64 + g * 8);
    *(bf16x8*)(xa + s * 128 + GOFF(g, s)) = v;
  }
  stage_chunk2(Wc, wb, 0, wave);
  __syncthreads();

#pragma unroll
  for (int cc = 0; cc < 2; ++cc) {
    stage_chunk2(Wc, wb, cc + 1, wave);
    const char* wbp = wb + (cc & 1) * 16384;
    const int brow = wave * 16 + lr;
    const bf16x8 b0 = *(const bf16x8*)(wbp + brow * 128 + GOFF(lg, brow));
    const bf16x8 b1 = *(const bf16x8*)(wbp + brow * 128 + GOFF(4 + lg, brow));
    const int ch = cc * 128 + brow;
#pragma unroll
    for (int m = 0; m < 4; ++m) {
      const int arow = m * 16 + lr;
      const bf16x8 a0 = *(const bf16x8*)(xa + arow * 128 + GOFF(lg, arow));
      const bf16x8 a1 = *(const bf16x8*)(xa + arow * 128 + GOFF(4 + lg, arow));
      f32x4 acc = {0.f, 0.f, 0.f, 0.f};
      acc = MFMA(a0, b0, acc);
      acc = MFMA(a1, b1, acc);
#pragma unroll
      for (int r = 0; r < 4; ++r) {
        const int s = m * 16 + lg * 4 + r;
        *(__bf16*)(act + s * 512 + GOFF(ch >> 3, s) + (ch & 7) * 2) =
            (__bf16)fast_tanh(acc[r] + bv1[cc]);
      }
    }
    __syncthreads();
  }

  f32x4 h2v[8];
#pragma unroll
  for (int cc = 0; cc < 8; ++cc) {
    const int c = cc + 2;
    if (c + 1 < 11) stage_chunk2(Wc, wb, c + 1, wave);
    const char* wbp = wb + (c & 1) * 16384;
    const int m = wave >> 1, n = wave & 1;
    const int brow = n * 16 + lr;
    const int arow = m * 16 + lr;
    f32x4 acc = {0.f, 0.f, 0.f, 0.f};
#pragma unroll
    for (int ks = 0; ks < 8; ++ks) {
      const int g = ks * 4 + lg;
      const bf16x8 a = *(const bf16x8*)(act + arow * 512 + GOFF(g, arow));
      const bf16x8 b = *(const bf16x8*)(wbp + brow * 512 + GOFF(g, brow));
      acc = MFMA(a, b, acc);
    }
#pragma unroll
    for (int r = 0; r < 4; ++r) h2v[cc][r] = fast_tanh(acc[r] + bv2[cc]);
    __syncthreads();
  }

  {
    const int m = wave >> 1, n = wave & 1;
#pragma unroll
    for (int cc = 0; cc < 8; ++cc) {
      const int ch = cc * 32 + n * 16 + lr;
#pragma unroll
      for (int r = 0; r < 4; ++r) {
        const int s = m * 16 + lg * 4 + r;
        *(__bf16*)(act + s * 512 + GOFF(ch >> 3, s) + (ch & 7) * 2) =
            (__bf16)h2v[cc][r];
      }
    }
  }
  stage_chunk2(Wc, wb, 11, wave);
  __syncthreads();

#pragma unroll
  for (int cc = 0; cc < 2; ++cc) {
    const char* wbp = wb + ((10 + cc) & 1) * 16384;
    const int m = wave >> 1, n = wave & 1;
    const int ch = cc * 32 + n * 16 + lr;
    const int brow = n * 16 + lr;
    const int arow = m * 16 + lr;
    f32x4 acc = {0.f, 0.f, 0.f, 0.f};
#pragma unroll
    for (int ks = 0; ks < 8; ++ks) {
      const int g = ks * 4 + lg;
      const bf16x8 a = *(const bf16x8*)(act + arow * 512 + GOFF(g, arow));
      const bf16x8 b = *(const bf16x8*)(wbp + brow * 512 + GOFF(g, brow));
      acc = MFMA(a, b, acc);
    }
#pragma unroll
    for (int r = 0; r < 4; ++r) {
      const int s = m * 16 + lg * 4 + r;
      xd[(size_t)(sb + s) * 64 + ch] = acc[r] + bv3[cc];
    }
  }
}

// ---------------- gemm_z v8: operand-swapped 128x128 tile, 4 WG/CU --------------
// A-operand = Woob rows (z cols), B-operand = g2 rows (samples).
// Epilogue: acc -> LDS T, then CACHED 16B stores (z slice stays in per-XCD L2
// for the matching apply dispatch).
#define GZ_SMEM 32768

__global__ __launch_bounds__(256, 4) void gemm_z_kernel(
    const __bf16* __restrict__ g2q, const __bf16* __restrict__ Woob,
    const float* __restrict__ boo, __bf16* __restrict__ zq, int bmper) {
  extern __shared__ char gsm[];
  const int tid = threadIdx.x;
  const int wave = tid >> 6, lane = tid & 63;
  const int lr = lane & 15, lg = lane >> 4;
  // XCD owns a contiguous bm range (g2 slice + Woob + z slice stay L2-resident)
  const int bm = (blockIdx.x & 7) * bmper + (blockIdx.x >> 7);
  const int bn = (blockIdx.x >> 3) & 15;
  const int wr = wave >> 1;      // woo-col half (64 cols)
  const int wc = wave & 1;       // sample half (64 samples)
  const int srl = lane >> 3, sch = lane & 7;

#define GZSTAGE(KT)                                                             \
  {                                                                             \
    _Pragma("unroll")                                                           \
    for (int j = 0; j < 4; ++j) {                                               \
      const int row = wave * 32 + j * 8 + srl;                                  \
      const int ka = (KT) * 64 + ((sch ^ (row & 7)) << 3);                      \
      gload_lds16(g2q + (size_t)(bm * 128 + row) * 256 + ka,                    \
                  gsm + wave * 4096 + j * 1024);                                \
      gload_lds16(Woob + (size_t)(bn * 128 + row) * 256 + ka,                   \
                  gsm + 16384 + wave * 4096 + j * 1024);                        \
    }                                                                           \
  }

  // bias per (fr, r): z col = bn*128 + wr*64 + fr*16 + lg*4 + r
  float bvf[4][4];
#pragma unroll
  for (int fr = 0; fr < 4; ++fr)
#pragma unroll
    for (int r = 0; r < 4; ++r) {
      const int col = bn * 128 + wr * 64 + fr * 16 + lg * 4 + r;
      bvf[fr][r] = (col < OFFD) ? boo[col] : 0.f;
    }

  f32x4 acc[4][4];
#pragma unroll
  for (int i = 0; i < 4; ++i)
#pragma unroll
    for (int j = 0; j < 4; ++j) acc[i][j] = (f32x4){0.f, 0.f, 0.f, 0.f};

  GZSTAGE(0)
  __syncthreads();

#pragma unroll
  for (int kt = 0; kt < 4; ++kt) {
    if (kt > 0) {
      GZSTAGE(kt)
      __syncthreads();
    }
    const char* Gb = gsm;            // g2 tile (samples)
    const char* Wb = gsm + 16384;    // Woob tile (z cols)
#pragma unroll
    for (int ks = 0; ks < 2; ++ks) {
      bf16x8 af[4], bfr[4];
#pragma unroll
      for (int f = 0; f < 4; ++f) {
        const int ra = wr * 64 + f * 16 + lr;            // woo-col rows (A)
        af[f] = *(const bf16x8*)(Wb + ra * 128 + GOFF(ks * 4 + lg, ra));
        const int rb = wc * 64 + f * 16 + lr;            // sample rows (B)
        bfr[f] = *(const bf16x8*)(Gb + rb * 128 + GOFF(ks * 4 + lg, rb));
      }
#pragma unroll
      for (int fr = 0; fr < 4; ++fr)
#pragma unroll
        for (int fc = 0; fc < 4; ++fc)
          acc[fr][fc] = MFMA(af[fr], bfr[fc], acc[fr][fc]);
    }
    __syncthreads();   // last iteration: staging reads certified before T reuse
  }

  // ---- epilogue: acc -> LDS T (row-major per sample), then 16B cached stores --
  {
    unsigned long long* Tq = (unsigned long long*)gsm;  // [128 rows][32 slots]
#pragma unroll
    for (int fc = 0; fc < 4; ++fc) {
      const int smp_l = wc * 64 + fc * 16 + lr;        // local sample row
#pragma unroll
      for (int fr = 0; fr < 4; ++fr) {
        const int s = wr * 16 + fr * 4 + lg;           // u64 slot (4 cols)
        const int sw = (s & ~7) | ((s & 7) ^ (smp_l & 7));
        Tq[smp_l * 32 + sw] =
            bfb64(acc[fr][fc][0] + bvf[fr][0], acc[fr][fc][1] + bvf[fr][1],
                  acc[fr][fc][2] + bvf[fr][2], acc[fr][fc][3] + bvf[fr][3]);
      }
    }
  }
  __syncthreads();

  {
    const unsigned long long* Tq = (const unsigned long long*)gsm;
#pragma unroll
    for (int it = 0; it < 8; ++it) {
      const int gi = tid + it * 256;     // 16B granule 0..2047
      const int row = gi >> 4;           // local sample row
      const int gcol = gi & 15;          // 16B granule within row
      const int s0 = gcol * 2, s1 = s0 + 1;
      const unsigned long long a =
          Tq[row * 32 + ((s0 & ~7) | ((s0 & 7) ^ (row & 7)))];
      const unsigned long long b =
          Tq[row * 32 + ((s1 & ~7) | ((s1 & 7) ^ (row & 7)))];
      u32x4 w;
      w.x = (unsigned)a; w.y = (unsigned)(a >> 32);
      w.z = (unsigned)b; w.w = (unsigned)(b >> 32);
      const int smp = bm * 128 + row;
      *(u32x4*)(zq + (size_t)smp * ZCOLS + bn * 128 + gcol * 8) = w;
    }
  }
}

// ---------------- apply v8: XCD-matched sample remap, 2 WG/CU --------------------
// WG blk on XCD (blk&7) handles samples produced by gemm_z XCD (blk&7):
// sb = s0base + (blk&7)*smpx + (blk>>3)*16, smpx = samples per XCD in slice.
#define APPLY_SMEM (65536 + 4096)
__global__ __launch_bounds__(512, 2) void apply_kernel(
    const __bf16* __restrict__ zq, const float* __restrict__ xd,
    const float* __restrict__ x0, float* __restrict__ out, int s0base, int smpx) {
  extern __shared__ char smem[];
  float* ys2 = (float*)(smem + 65536);

  const int tid = threadIdx.x;
  const int wave = tid >> 6, lane = tid & 63;
  const int blk = blockIdx.x;
  const int sloc = (blk & 7) * smpx + (blk >> 3) * 16;   // slice-local base
  const int sb = s0base + sloc;
  const int s0 = wave * 2, s1 = s0 + 1;

  const float x0vA = x0[(size_t)(sb + s0) * 64 + lane];
  const float x0vB = x0[(size_t)(sb + s1) * 64 + lane];
  const float xdA = xd[(size_t)(sb + s0) * 64 + lane];
  const float xdB = xd[(size_t)(sb + s1) * 64 + lane];

  // linear stage: 2 sample rows (4096 B each) per wave (z indexed slice-local)
  {
    const char* srcA = (const char*)(zq + (size_t)(sloc + s0) * ZCOLS);
    char* dstA = smem + wave * 8192;
#pragma unroll
    for (int j = 0; j < 4; ++j) {
      gload_lds16(srcA + j * 1024 + lane * 16, dstA + j * 1024);
      gload_lds16(srcA + ZROWB + j * 1024 + lane * 16, dstA + 4096 + j * 1024);
    }
  }
  asm volatile("s_waitcnt vmcnt(0)" ::: "memory");
  SB0();

  const __bf16* zsA = (const __bf16*)(smem + wave * 8192);
  const __bf16* zsB = zsA + ZCOLS;

  // pass 1: y_j = xd_j x0_j + sum_{k>j} z[k(k-1)/2 + j] x0_k   (j = lane)
  float yA = xdA * x0vA, yB = xdB * x0vB;
  int rs = 0;
#pragma unroll
  for (int k = 1; k < 64; ++k) {
    const float zA = (float)zsA[rs + lane];
    const float zB = (float)zsB[rs + lane];
    const float xkA = lane_bcast(x0vA, k);
    const float xkB = lane_bcast(x0vB, k);
    const bool mv = lane < k;
    yA += mv ? zA * xkA : 0.f;
    yB += mv ? zB * xkB : 0.f;
    rs += k;
  }

  float* ypA = ys2 + wave * 128;
  float* ypB = ypA + 64;
  ypA[lane] = yA;
  ypB[lane] = yB;
  asm volatile("s_waitcnt lgkmcnt(0)" ::: "memory");
  SB0();

  // pass 2: D_i = xd_i y_i + sum_{j<i} z[i(i-1)/2 + j] y_j   (i = lane)
  float DA = xdA * yA, DB = xdB * yB;
  {
    const int base = (lane * (lane - 1)) >> 1;
    const int nf = lane >> 3;
    const int t = lane & 7;
    const char* zrA = (const char*)zsA + base * 2;
    const char* zrB = (const char*)zsB + base * 2;
    for (int c = 0; c < nf; ++c) {
      const uint4 wA = *(const uint4*)(zrA + c * 16);
      const uint4 wB = *(const uint4*)(zrB + c * 16);
      const float4 u0 = *(const float4*)(ypA + c * 8);
      const float4 u1 = *(const float4*)(ypA + c * 8 + 4);
      const float4 v0 = *(const float4*)(ypB + c * 8);
      const float4 v1 = *(const float4*)(ypB + c * 8 + 4);
      DA += bf_lo(wA.x) * u0.x + bf_hi(wA.x) * u0.y + bf_lo(wA.y) * u0.z +
            bf_hi(wA.y) * u0.w + bf_lo(wA.z) * u1.x + bf_hi(wA.z) * u1.y +
            bf_lo(wA.w) * u1.z + bf_hi(wA.w) * u1.w;
      DB += bf_lo(wB.x) * v0.x + bf_hi(wB.x) * v0.y + bf_lo(wB.y) * v0.z +
            bf_hi(wB.y) * v0.w + bf_lo(wB.z) * v1.x + bf_hi(wB.z) * v1.y +
            bf_lo(wB.w) * v1.z + bf_hi(wB.w) * v1.w;
    }
    if (t) {
      const uint4 wA = *(const uint4*)(zrA + nf * 16);
      const uint4 wB = *(const uint4*)(zrB + nf * 16);
      const float4 u0 = *(const float4*)(ypA + nf * 8);
      const float4 u1 = *(const float4*)(ypA + nf * 8 + 4);
      const float4 v0 = *(const float4*)(ypB + nf * 8);
      const float4 v1 = *(const float4*)(ypB + nf * 8 + 4);
      DA += ((0 < t) ? bf_lo(wA.x) * u0.x : 0.f) + ((1 < t) ? bf_hi(wA.x) * u0.y : 0.f) +
            ((2 < t) ? bf_lo(wA.y) * u0.z : 0.f) + ((3 < t) ? bf_hi(wA.y) * u0.w : 0.f) +
            ((4 < t) ? bf_lo(wA.z) * u1.x : 0.f) + ((5 < t) ? bf_hi(wA.z) * u1.y : 0.f) +
            ((6 < t) ? bf_lo(wA.w) * u1.z : 0.f);
      DB += ((0 < t) ? bf_lo(wB.x) * v0.x : 0.f) + ((1 < t) ? bf_hi(wB.x) * v0.y : 0.f) +
            ((2 < t) ? bf_lo(wB.y) * v0.z : 0.f) + ((3 < t) ? bf_hi(wB.y) * v0.w : 0.f) +
            ((4 < t) ? bf_lo(wB.z) * v1.x : 0.f) + ((5 < t) ? bf_hi(wB.z) * v1.y : 0.f) +
            ((6 < t) ? bf_lo(wB.w) * v1.z : 0.f);
    }
  }
  __builtin_nontemporal_store(DA, out + (size_t)(sb + s0) * 64 + lane);
  __builtin_nontemporal_store(DB, out + (size_t)(sb + s1) * 64 + lane);
}

// ---------------- launch ----------------
extern "C" void kernel_launch(void* const* d_in, const int* in_sizes, int n_in,
                              void* d_out, int out_size, void* d_ws, size_t ws_size,
                              hipStream_t stream) {
  const float* x   = (const float*)d_in[0];
  const float* Wd1 = (const float*)d_in[1];
  const float* bd1 = (const float*)d_in[2];
  const float* Wd2 = (const float*)d_in[3];
  const float* bd2 = (const float*)d_in[4];
  const float* Wdo = (const float*)d_in[5];
  const float* bdo = (const float*)d_in[6];
  const float* Wo1 = (const float*)d_in[7];
  const float* bo1 = (const float*)d_in[8];
  const float* Wo2 = (const float*)d_in[9];
  const float* bo2 = (const float*)d_in[10];
  const float* Woo = (const float*)d_in[11];
  const float* boo = (const float*)d_in[12];
  float* out = (float*)d_out;

  char* ws = (char*)d_ws;
  // Wcat (bf16 elems): Wo1@0 | Wo2@16384 | Wd1@81920 | Wd2@98304 | Wdo@163840
  __bf16* Wcat = (__bf16*)(ws + 0);          //   360448 B
  __bf16* Woob = (__bf16*)(ws + 360448);     //  1048576 B (zero-padded rows)
  __bf16* g2   = (__bf16*)(ws + 1409024);    // 16777216 B
  float*  xdp  = (float*)(ws + 18186240);    //  8388608 B
  const size_t zoff = 26574848;
  __bf16* zq   = (__bf16*)(ws + zoff);       // z slice buffer [QSs][2048] bf16

  const size_t zcap = (ws_size > zoff) ? (ws_size - zoff) : 0;
  int nslices = 8;
  if (zcap >= (size_t)(B_TOT / 4) * ZROWB) nslices = 4;
  const int QSs = B_TOT / nslices;
  const int nbm = QSs / 128;       // 128-sample tiles
  const int bmper = nbm >> 3;      // bm tiles per XCD
  const int smpx = bmper * 128;    // samples per XCD in a slice

  cast_all_kernel<<<512, 256, 0, stream>>>(
      Wo1, Wcat, HDIM * NDIM,
      Wo2, Wcat + 16384, HDIM * HDIM,
      Wd1, Wcat + 81920, HDIM * NDIM,
      Wd2, Wcat + 98304, HDIM * HDIM,
      Wdo, Wcat + 163840, NDIM * HDIM,
      Woo, Woob, OFFD * HDIM,
      Woob + OFFD * HDIM, 32 * HDIM);

  (void)hipFuncSetAttribute((const void*)off_trunk_kernel,
                            hipFuncAttributeMaxDynamicSharedMemorySize, TRK_SMEM);
  (void)hipFuncSetAttribute((const void*)diag_trunk_kernel,
                            hipFuncAttributeMaxDynamicSharedMemorySize, TRK_SMEM);
  off_trunk_kernel<<<B_TOT / 64, 512, TRK_SMEM, stream>>>(
      x, Wcat, bo1, bo2, g2);
  diag_trunk_kernel<<<B_TOT / 64, 512, TRK_SMEM, stream>>>(
      x, Wcat + 81920, bd1, bd2, bdo, xdp);

  (void)hipFuncSetAttribute((const void*)gemm_z_kernel,
                            hipFuncAttributeMaxDynamicSharedMemorySize, GZ_SMEM);
  (void)hipFuncSetAttribute((const void*)apply_kernel,
                            hipFuncAttributeMaxDynamicSharedMemorySize, APPLY_SMEM);
  for (int s = 0; s < nslices; ++s) {
    gemm_z_kernel<<<nbm * 16, 256, GZ_SMEM, stream>>>(
        g2 + (size_t)s * QSs * HDIM, Woob, boo, zq, bmper);
    apply_kernel<<<QSs / 16, 512, APPLY_SMEM, stream>>>(
        zq, xdp, x, out, s * QSs, smpx);
  }
}

// Round 25
// 146.192 us; speedup vs baseline: 1.1997x; 1.1997x over previous
//
#include <hip/hip_runtime.h>
#include <math.h>

// Damping: B=32768, N=64, H=256, OFF=2016
//   diag: x -> tanh(Wd1) -> tanh(Wd2) -> Wdo   (64 per sample)
//   off : x -> tanh(Wo1) -> tanh(Wo2) -> Woo   (2016 per sample, strict lower tri)
//   out = L (L^T x0), L diag = xd, L[i][j](j<i) = z[i(i-1)/2+j]
//
// z path v7: gemm_z (128x128 tile, operand-swapped MFMA, LDS row-transpose
// epilogue -> NON-TEMPORAL full-line 16B stores) -> plain z[s][2048] -> apply.

#define B_TOT 32768
#define NDIM  64
#define HDIM  256
#define OFFD  2016
#define ZCOLS 2048                 // padded row length (bf16)
#define ZROWB 4096                 // bytes per z row

typedef __bf16 bf16x8 __attribute__((ext_vector_type(8)));
typedef float  f32x4  __attribute__((ext_vector_type(4)));
typedef unsigned u32x4 __attribute__((ext_vector_type(4)));

__device__ __forceinline__ float fast_tanh(float x) {
  float e = __expf(2.f * x);
  return 1.f - 2.f * __builtin_amdgcn_rcpf(e + 1.f);
}
__device__ __forceinline__ float lane_bcast(float v, int l) {
  return __uint_as_float(__builtin_amdgcn_readlane(__float_as_uint(v), l));
}
__device__ __forceinline__ float bf_lo(unsigned w) { return __uint_as_float(w << 16); }
__device__ __forceinline__ float bf_hi(unsigned w) { return __uint_as_float(w & 0xffff0000u); }
__device__ __forceinline__ unsigned long long bfb64(float a, float b, float c, float d) {
  __bf16 ha = (__bf16)a, hb = (__bf16)b, hc = (__bf16)c, hd = (__bf16)d;
  return (unsigned long long)__builtin_bit_cast(unsigned short, ha) |
         ((unsigned long long)__builtin_bit_cast(unsigned short, hb) << 16) |
         ((unsigned long long)__builtin_bit_cast(unsigned short, hc) << 32) |
         ((unsigned long long)__builtin_bit_cast(unsigned short, hd) << 48);
}

__device__ __forceinline__ void gload_lds16(const void* g, void* l) {
  __builtin_amdgcn_global_load_lds(
      (const __attribute__((address_space(1))) unsigned*)g,
      (__attribute__((address_space(3))) unsigned*)l, 16, 0, 0);
}

#define MFMA(A, B, C) __builtin_amdgcn_mfma_f32_16x16x32_bf16((A), (B), (C), 0, 0, 0)
#define SB0() __builtin_amdgcn_sched_barrier(0)
// XOR-swizzled 16B-granule byte offset within a row (low 3 bits of granule)
#define GOFF(g, row) (((((g) & ~7) | (((g) & 7) ^ ((row) & 7)))) << 4)

// ---------------- weight cast (f32 -> bf16) + Woob pad zero-fill ----------------
__device__ __forceinline__ void cast_range(const float* __restrict__ s,
                                           __bf16* __restrict__ d, int n) {
  int i = blockIdx.x * blockDim.x + threadIdx.x;
  const int stride = gridDim.x * blockDim.x;
  for (; i < n; i += stride) d[i] = (__bf16)s[i];
}
__global__ __launch_bounds__(256) void cast_all_kernel(
    const float* s0, __bf16* d0, int n0, const float* s1, __bf16* d1, int n1,
    const float* s2, __bf16* d2, int n2, const float* s3, __bf16* d3, int n3,
    const float* s4, __bf16* d4, int n4, const float* s5, __bf16* d5, int n5,
    __bf16* d6, int n6) {
  cast_range(s0, d0, n0); cast_range(s1, d1, n1); cast_range(s2, d2, n2);
  cast_range(s3, d3, n3); cast_range(s4, d4, n4); cast_range(s5, d5, n5);
  int i = blockIdx.x * blockDim.x + threadIdx.x;
  const int stride = gridDim.x * blockDim.x;
  for (; i < n6; i += stride) d6[i] = (__bf16)0.f;
}

__device__ __forceinline__ bf16x8 cvt8(const float* __restrict__ p) {
  const float4 u = *(const float4*)p;
  const float4 v = *(const float4*)(p + 4);
  bf16x8 r;
  r[0] = (__bf16)u.x; r[1] = (__bf16)u.y; r[2] = (__bf16)u.z; r[3] = (__bf16)u.w;
  r[4] = (__bf16)v.x; r[5] = (__bf16)v.y; r[6] = (__bf16)v.z; r[7] = (__bf16)v.w;
  return r;
}

// ---------------- shared trunk machinery: 64 samples/WG, 72KB LDS, 2 WG/CU ------
#define TRK_SMEM (8192 + 32768 + 32768)

// stage one 16KB weight chunk; rows are 128B if c<2 else 512B
__device__ __forceinline__ void stage_chunk2(const char* wreg, char* wb,
                                             int c, int wave) {
  const char* base = wreg + (size_t)c * 16384;
  char* dst = wb + (c & 1) * 16384;
  const int lane = threadIdx.x & 63;
  const int s0 = wave * 64 + lane;
  const int s1 = s0 + 512;
  if (c < 2) {  // 128-byte rows (8 granules)
    const int r0 = s0 >> 3, q0 = (s0 & 7) ^ (r0 & 7);
    gload_lds16(base + r0 * 128 + (q0 << 4), dst + wave * 1024);
    const int r1 = s1 >> 3, q1 = (s1 & 7) ^ (r1 & 7);
    gload_lds16(base + r1 * 128 + (q1 << 4), dst + (wave + 8) * 1024);
  } else {      // 512-byte rows (32 granules)
    const int r0 = s0 >> 5, g0 = s0 & 31;
    const int q0 = (g0 & 24) | ((g0 & 7) ^ (r0 & 7));
    gload_lds16(base + r0 * 512 + (q0 << 4), dst + wave * 1024);
    const int r1 = s1 >> 5, g1 = s1 & 31;
    const int q1 = (g1 & 24) | ((g1 & 7) ^ (r1 & 7));
    gload_lds16(base + r1 * 512 + (q1 << 4), dst + (wave + 8) * 1024);
  }
}

// ---------------- off_trunk: x -> tanh(Wo1) -> tanh(Wo2) -> g2 ------------------
__global__ __launch_bounds__(512, 2) void off_trunk_kernel(
    const float* __restrict__ x, const __bf16* __restrict__ Wreg,
    const float* __restrict__ bo1, const float* __restrict__ bo2,
    __bf16* __restrict__ g2) {
  extern __shared__ char smem[];
  char* xa  = smem;            // 8 KB
  char* act = smem + 8192;     // 32 KB (g1)
  char* wb  = smem + 40960;    // 32 KB
  const char* Wc = (const char*)Wreg;

  const int tid = threadIdx.x;
  const int wave = tid >> 6, lane = tid & 63;
  const int lr = lane & 15, lg = lane >> 4;
  const int sb = blockIdx.x * 64;

  float bv1[2], bv2[8];
#pragma unroll
  for (int cc = 0; cc < 2; ++cc) bv1[cc] = bo1[cc * 128 + wave * 16 + lr];
#pragma unroll
  for (int cc = 0; cc < 8; ++cc) bv2[cc] = bo2[cc * 32 + (wave & 1) * 16 + lr];

  {
    const int s = tid >> 3, g = tid & 7;
    const bf16x8 v = cvt8(x + (size_t)(sb + s) * 64 + g * 8);
    *(bf16x8*)(xa + s * 128 + GOFF(g, s)) = v;
  }
  stage_chunk2(Wc, wb, 0, wave);
  __syncthreads();

#pragma unroll
  for (int cc = 0; cc < 2; ++cc) {
    stage_chunk2(Wc, wb, cc + 1, wave);
    const char* wbp = wb + (cc & 1) * 16384;
    const int brow = wave * 16 + lr;
    const bf16x8 b0 = *(const bf16x8*)(wbp + brow * 128 + GOFF(lg, brow));
    const bf16x8 b1 = *(const bf16x8*)(wbp + brow * 128 + GOFF(4 + lg, brow));
    const int ch = cc * 128 + brow;
#pragma unroll
    for (int m = 0; m < 4; ++m) {
      const int arow = m * 16 + lr;
      const bf16x8 a0 = *(const bf16x8*)(xa + arow * 128 + GOFF(lg, arow));
      const bf16x8 a1 = *(const bf16x8*)(xa + arow * 128 + GOFF(4 + lg, arow));
      f32x4 acc = {0.f, 0.f, 0.f, 0.f};
      acc = MFMA(a0, b0, acc);
      acc = MFMA(a1, b1, acc);
#pragma unroll
      for (int r = 0; r < 4; ++r) {
        const int s = m * 16 + lg * 4 + r;
        *(__bf16*)(act + s * 512 + GOFF(ch >> 3, s) + (ch & 7) * 2) =
            (__bf16)fast_tanh(acc[r] + bv1[cc]);
      }
    }
    __syncthreads();
  }

#pragma unroll
  for (int cc = 0; cc < 8; ++cc) {
    const int c = cc + 2;
    if (c + 1 < 10) stage_chunk2(Wc, wb, c + 1, wave);
    const char* wbp = wb + (c & 1) * 16384;
    const int m = wave >> 1, n = wave & 1;
    const int ch = cc * 32 + n * 16 + lr;
    const int brow = n * 16 + lr;
    const int arow = m * 16 + lr;
    f32x4 acc = {0.f, 0.f, 0.f, 0.f};
#pragma unroll
    for (int ks = 0; ks < 8; ++ks) {
      const int g = ks * 4 + lg;
      const bf16x8 a = *(const bf16x8*)(act + arow * 512 + GOFF(g, arow));
      const bf16x8 b = *(const bf16x8*)(wbp + brow * 512 + GOFF(g, brow));
      acc = MFMA(a, b, acc);
    }
#pragma unroll
    for (int r = 0; r < 4; ++r) {
      const int s = m * 16 + lg * 4 + r;
      g2[(size_t)(sb + s) * 256 + ch] = (__bf16)fast_tanh(acc[r] + bv2[cc]);
    }
    if (cc < 7) __syncthreads();
  }
}

// ---------------- diag_trunk: x -> tanh(Wd1) -> tanh(Wd2) -> Wdo -> xd ----------
__global__ __launch_bounds__(512, 2) void diag_trunk_kernel(
    const float* __restrict__ x, const __bf16* __restrict__ Wreg,
    const float* __restrict__ bd1, const float* __restrict__ bd2,
    const float* __restrict__ bdo, float* __restrict__ xd) {
  extern __shared__ char smem[];
  char* xa  = smem;            // 8 KB
  char* act = smem + 8192;     // 32 KB (h1, then h2)
  char* wb  = smem + 40960;    // 32 KB
  const char* Wc = (const char*)Wreg;

  const int tid = threadIdx.x;
  const int wave = tid >> 6, lane = tid & 63;
  const int lr = lane & 15, lg = lane >> 4;
  const int sb = blockIdx.x * 64;

  float bv1[2], bv2[8], bv3[2];
#pragma unroll
  for (int cc = 0; cc < 2; ++cc) bv1[cc] = bd1[cc * 128 + wave * 16 + lr];
#pragma unroll
  for (int cc = 0; cc < 8; ++cc) bv2[cc] = bd2[cc * 32 + (wave & 1) * 16 + lr];
#pragma unroll
  for (int cc = 0; cc < 2; ++cc) bv3[cc] = bdo[cc * 32 + (wave & 1) * 16 + lr];

  {
    const int s = tid >> 3, g = tid & 7;
    const bf16x8 v = cvt8(x + (size_t)(sb + s) * 64 + g * 8);
    *(bf16x8*)(xa + s * 128 + GOFF(g, s)) = v;
  }
  stage_chunk2(Wc, wb, 0, wave);
  __syncthreads();

#pragma unroll
  for (int cc = 0; cc < 2; ++cc) {
    stage_chunk2(Wc, wb, cc + 1, wave);
    const char* wbp = wb + (cc & 1) * 16384;
    const int brow = wave * 16 + lr;
    const bf16x8 b0 = *(const bf16x8*)(wbp + brow * 128 + GOFF(lg, brow));
    const bf16x8 b1 = *(const bf16x8*)(wbp + brow * 128 + GOFF(4 + lg, brow));
    const int ch = cc * 128 + brow;
#pragma unroll
    for (int m = 0; m < 4; ++m) {
      const int arow = m * 16 + lr;
      const bf16x8 a0 = *(const bf16x8*)(xa + arow * 128 + GOFF(lg, arow));
      const bf16x8 a1 = *(const bf16x8*)(xa + arow * 128 + GOFF(4 + lg, arow));
      f32x4 acc = {0.f, 0.f, 0.f, 0.f};
      acc = MFMA(a0, b0, acc);
      acc = MFMA(a1, b1, acc);
#pragma unroll
      for (int r = 0; r < 4; ++r) {
        const int s = m * 16 + lg * 4 + r;
        *(__bf16*)(act + s * 512 + GOFF(ch >> 3, s) + (ch & 7) * 2) =
            (__bf16)fast_tanh(acc[r] + bv1[cc]);
      }
    }
    __syncthreads();
  }

  f32x4 h2v[8];
#pragma unroll
  for (int cc = 0; cc < 8; ++cc) {
    const int c = cc + 2;
    if (c + 1 < 11) stage_chunk2(Wc, wb, c + 1, wave);
    const char* wbp = wb + (c & 1) * 16384;
    const int m = wave >> 1, n = wave & 1;
    const int brow = n * 16 + lr;
    const int arow = m * 16 + lr;
    f32x4 acc = {0.f, 0.f, 0.f, 0.f};
#pragma unroll
    for (int ks = 0; ks < 8; ++ks) {
      const int g = ks * 4 + lg;
      const bf16x8 a = *(const bf16x8*)(act + arow * 512 + GOFF(g, arow));
      const bf16x8 b = *(const bf16x8*)(wbp + brow * 512 + GOFF(g, brow));
      acc = MFMA(a, b, acc);
    }
#pragma unroll
    for (int r = 0; r < 4; ++r) h2v[cc][r] = fast_tanh(acc[r] + bv2[cc]);
    __syncthreads();
  }

  {
    const int m = wave >> 1, n = wave & 1;
#pragma unroll
    for (int cc = 0; cc < 8; ++cc) {
      const int ch = cc * 32 + n * 16 + lr;
#pragma unroll
      for (int r = 0; r < 4; ++r) {
        const int s = m * 16 + lg * 4 + r;
        *(__bf16*)(act + s * 512 + GOFF(ch >> 3, s) + (ch & 7) * 2) =
            (__bf16)h2v[cc][r];
      }
    }
  }
  stage_chunk2(Wc, wb, 11, wave);
  __syncthreads();

#pragma unroll
  for (int cc = 0; cc < 2; ++cc) {
    const char* wbp = wb + ((10 + cc) & 1) * 16384;
    const int m = wave >> 1, n = wave & 1;
    const int ch = cc * 32 + n * 16 + lr;
    const int brow = n * 16 + lr;
    const int arow = m * 16 + lr;
    f32x4 acc = {0.f, 0.f, 0.f, 0.f};
#pragma unroll
    for (int ks = 0; ks < 8; ++ks) {
      const int g = ks * 4 + lg;
      const bf16x8 a = *(const bf16x8*)(act + arow * 512 + GOFF(g, arow));
      const bf16x8 b = *(const bf16x8*)(wbp + brow * 512 + GOFF(g, brow));
      acc = MFMA(a, b, acc);
    }
#pragma unroll
    for (int r = 0; r < 4; ++r) {
      const int s = m * 16 + lg * 4 + r;
      xd[(size_t)(sb + s) * 64 + ch] = acc[r] + bv3[cc];
    }
  }
}

// ---------------- gemm_z v7: operand-swapped 128x128 tile, 4 WG/CU --------------
// A-operand = Woob rows (z cols), B-operand = g2 rows (samples).
// Epilogue: acc -> LDS T[128 smp][32 u64 slots] (swizzled), then NON-TEMPORAL
// 16B stores (streaming z bypasses L2 -> no write-allocate / eviction churn).
#define GZ_SMEM 32768

__global__ __launch_bounds__(256, 4) void gemm_z_kernel(
    const __bf16* __restrict__ g2q, const __bf16* __restrict__ Woob,
    const float* __restrict__ boo, __bf16* __restrict__ zq, int bmper) {
  extern __shared__ char gsm[];
  const int tid = threadIdx.x;
  const int wave = tid >> 6, lane = tid & 63;
  const int lr = lane & 15, lg = lane >> 4;
  // XCD owns a contiguous bm range (g2 slice + Woob stay L2-resident)
  const int bm = (blockIdx.x & 7) * bmper + (blockIdx.x >> 7);
  const int bn = (blockIdx.x >> 3) & 15;
  const int wr = wave >> 1;      // woo-col half (64 cols)
  const int wc = wave & 1;       // sample half (64 samples)
  const int srl = lane >> 3, sch = lane & 7;

#define GZSTAGE(KT)                                                             \
  {                                                                             \
    _Pragma("unroll")                                                           \
    for (int j = 0; j < 4; ++j) {                                               \
      const int row = wave * 32 + j * 8 + srl;                                  \
      const int ka = (KT) * 64 + ((sch ^ (row & 7)) << 3);                      \
      gload_lds16(g2q + (size_t)(bm * 128 + row) * 256 + ka,                    \
                  gsm + wave * 4096 + j * 1024);                                \
      gload_lds16(Woob + (size_t)(bn * 128 + row) * 256 + ka,                   \
                  gsm + 16384 + wave * 4096 + j * 1024);                        \
    }                                                                           \
  }

  // bias per (fr, r): z col = bn*128 + wr*64 + fr*16 + lg*4 + r
  float bvf[4][4];
#pragma unroll
  for (int fr = 0; fr < 4; ++fr)
#pragma unroll
    for (int r = 0; r < 4; ++r) {
      const int col = bn * 128 + wr * 64 + fr * 16 + lg * 4 + r;
      bvf[fr][r] = (col < OFFD) ? boo[col] : 0.f;
    }

  f32x4 acc[4][4];
#pragma unroll
  for (int i = 0; i < 4; ++i)
#pragma unroll
    for (int j = 0; j < 4; ++j) acc[i][j] = (f32x4){0.f, 0.f, 0.f, 0.f};

  GZSTAGE(0)
  __syncthreads();

#pragma unroll
  for (int kt = 0; kt < 4; ++kt) {
    if (kt > 0) {
      GZSTAGE(kt)
      __syncthreads();
    }
    const char* Gb = gsm;            // g2 tile (samples)
    const char* Wb = gsm + 16384;    // Woob tile (z cols)
#pragma unroll
    for (int ks = 0; ks < 2; ++ks) {
      bf16x8 af[4], bfr[4];
#pragma unroll
      for (int f = 0; f < 4; ++f) {
        const int ra = wr * 64 + f * 16 + lr;            // woo-col rows (A)
        af[f] = *(const bf16x8*)(Wb + ra * 128 + GOFF(ks * 4 + lg, ra));
        const int rb = wc * 64 + f * 16 + lr;            // sample rows (B)
        bfr[f] = *(const bf16x8*)(Gb + rb * 128 + GOFF(ks * 4 + lg, rb));
      }
#pragma unroll
      for (int fr = 0; fr < 4; ++fr)
#pragma unroll
        for (int fc = 0; fc < 4; ++fc)
          acc[fr][fc] = MFMA(af[fr], bfr[fc], acc[fr][fc]);
    }
    __syncthreads();   // last iteration: staging reads certified before T reuse
  }

  // ---- epilogue: acc -> LDS T (row-major per sample), then NT 16B stores ----
  {
    unsigned long long* Tq = (unsigned long long*)gsm;  // [128 rows][32 slots]
#pragma unroll
    for (int fc = 0; fc < 4; ++fc) {
      const int smp_l = wc * 64 + fc * 16 + lr;        // local sample row
#pragma unroll
      for (int fr = 0; fr < 4; ++fr) {
        const int s = wr * 16 + fr * 4 + lg;           // u64 slot (4 cols)
        const int sw = (s & ~7) | ((s & 7) ^ (smp_l & 7));
        Tq[smp_l * 32 + sw] =
            bfb64(acc[fr][fc][0] + bvf[fr][0], acc[fr][fc][1] + bvf[fr][1],
                  acc[fr][fc][2] + bvf[fr][2], acc[fr][fc][3] + bvf[fr][3]);
      }
    }
  }
  __syncthreads();

  {
    const unsigned long long* Tq = (const unsigned long long*)gsm;
#pragma unroll
    for (int it = 0; it < 8; ++it) {
      const int gi = tid + it * 256;     // 16B granule 0..2047
      const int row = gi >> 4;           // local sample row
      const int gcol = gi & 15;          // 16B granule within row
      const int s0 = gcol * 2, s1 = s0 + 1;
      const unsigned long long a =
          Tq[row * 32 + ((s0 & ~7) | ((s0 & 7) ^ (row & 7)))];
      const unsigned long long b =
          Tq[row * 32 + ((s1 & ~7) | ((s1 & 7) ^ (row & 7)))];
      u32x4 w;
      w.x = (unsigned)a; w.y = (unsigned)(a >> 32);
      w.z = (unsigned)b; w.w = (unsigned)(b >> 32);
      const int smp = bm * 128 + row;
      __builtin_nontemporal_store(
          w, (u32x4*)(zq + (size_t)smp * ZCOLS + bn * 128 + gcol * 8));
    }
  }
}

// ---------------- apply v4: 512 thr, 16 samples, plain-row stage, 2 WG/CU -------
// LDS: zs 16 x 4096B = 64KB | ys 8 x 128 f32 = 4KB
#define APPLY_SMEM (65536 + 4096)
__global__ __launch_bounds__(512, 2) void apply_kernel(
    const __bf16* __restrict__ zq, const float* __restrict__ xd,
    const float* __restrict__ x0, float* __restrict__ out, int s0base) {
  extern __shared__ char smem[];
  float* ys2 = (float*)(smem + 65536);

  const int tid = threadIdx.x;
  const int wave = tid >> 6, lane = tid & 63;
  const int sb = s0base + blockIdx.x * 16;
  const int s0 = wave * 2, s1 = s0 + 1;

  const float x0vA = x0[(size_t)(sb + s0) * 64 + lane];
  const float x0vB = x0[(size_t)(sb + s1) * 64 + lane];
  const float xdA = xd[(size_t)(sb + s0) * 64 + lane];
  const float xdB = xd[(size_t)(sb + s1) * 64 + lane];

  // linear stage: 2 sample rows (4096 B each) per wave
  {
    const char* srcA = (const char*)(zq + (size_t)(sb + s0) * ZCOLS);
    char* dstA = smem + wave * 8192;
#pragma unroll
    for (int j = 0; j < 4; ++j) {
      gload_lds16(srcA + j * 1024 + lane * 16, dstA + j * 1024);
      gload_lds16(srcA + ZROWB + j * 1024 + lane * 16, dstA + 4096 + j * 1024);
    }
  }
  asm volatile("s_waitcnt vmcnt(0)" ::: "memory");
  SB0();

  const __bf16* zsA = (const __bf16*)(smem + wave * 8192);
  const __bf16* zsB = zsA + ZCOLS;

  // pass 1: y_j = xd_j x0_j + sum_{k>j} z[k(k-1)/2 + j] x0_k   (j = lane)
  float yA = xdA * x0vA, yB = xdB * x0vB;
  int rs = 0;
#pragma unroll
  for (int k = 1; k < 64; ++k) {
    const float zA = (float)zsA[rs + lane];
    const float zB = (float)zsB[rs + lane];
    const float xkA = lane_bcast(x0vA, k);
    const float xkB = lane_bcast(x0vB, k);
    const bool mv = lane < k;
    yA += mv ? zA * xkA : 0.f;
    yB += mv ? zB * xkB : 0.f;
    rs += k;
  }

  float* ypA = ys2 + wave * 128;
  float* ypB = ypA + 64;
  ypA[lane] = yA;
  ypB[lane] = yB;
  asm volatile("s_waitcnt lgkmcnt(0)" ::: "memory");
  SB0();

  // pass 2: D_i = xd_i y_i + sum_{j<i} z[i(i-1)/2 + j] y_j   (i = lane)
  float DA = xdA * yA, DB = xdB * yB;
  {
    const int base = (lane * (lane - 1)) >> 1;
    const int nf = lane >> 3;
    const int t = lane & 7;
    const char* zrA = (const char*)zsA + base * 2;
    const char* zrB = (const char*)zsB + base * 2;
    for (int c = 0; c < nf; ++c) {
      const uint4 wA = *(const uint4*)(zrA + c * 16);
      const uint4 wB = *(const uint4*)(zrB + c * 16);
      const float4 u0 = *(const float4*)(ypA + c * 8);
      const float4 u1 = *(const float4*)(ypA + c * 8 + 4);
      const float4 v0 = *(const float4*)(ypB + c * 8);
      const float4 v1 = *(const float4*)(ypB + c * 8 + 4);
      DA += bf_lo(wA.x) * u0.x + bf_hi(wA.x) * u0.y + bf_lo(wA.y) * u0.z +
            bf_hi(wA.y) * u0.w + bf_lo(wA.z) * u1.x + bf_hi(wA.z) * u1.y +
            bf_lo(wA.w) * u1.z + bf_hi(wA.w) * u1.w;
      DB += bf_lo(wB.x) * v0.x + bf_hi(wB.x) * v0.y + bf_lo(wB.y) * v0.z +
            bf_hi(wB.y) * v0.w + bf_lo(wB.z) * v1.x + bf_hi(wB.z) * v1.y +
            bf_lo(wB.w) * v1.z + bf_hi(wB.w) * v1.w;
    }
    if (t) {
      const uint4 wA = *(const uint4*)(zrA + nf * 16);
      const uint4 wB = *(const uint4*)(zrB + nf * 16);
      const float4 u0 = *(const float4*)(ypA + nf * 8);
      const float4 u1 = *(const float4*)(ypA + nf * 8 + 4);
      const float4 v0 = *(const float4*)(ypB + nf * 8);
      const float4 v1 = *(const float4*)(ypB + nf * 8 + 4);
      DA += ((0 < t) ? bf_lo(wA.x) * u0.x : 0.f) + ((1 < t) ? bf_hi(wA.x) * u0.y : 0.f) +
            ((2 < t) ? bf_lo(wA.y) * u0.z : 0.f) + ((3 < t) ? bf_hi(wA.y) * u0.w : 0.f) +
            ((4 < t) ? bf_lo(wA.z) * u1.x : 0.f) + ((5 < t) ? bf_hi(wA.z) * u1.y : 0.f) +
            ((6 < t) ? bf_lo(wA.w) * u1.z : 0.f);
      DB += ((0 < t) ? bf_lo(wB.x) * v0.x : 0.f) + ((1 < t) ? bf_hi(wB.x) * v0.y : 0.f) +
            ((2 < t) ? bf_lo(wB.y) * v0.z : 0.f) + ((3 < t) ? bf_hi(wB.y) * v0.w : 0.f) +
            ((4 < t) ? bf_lo(wB.z) * v1.x : 0.f) + ((5 < t) ? bf_hi(wB.z) * v1.y : 0.f) +
            ((6 < t) ? bf_lo(wB.w) * v1.z : 0.f);
    }
  }
  __builtin_nontemporal_store(DA, out + (size_t)(sb + s0) * 64 + lane);
  __builtin_nontemporal_store(DB, out + (size_t)(sb + s1) * 64 + lane);
}

// ---------------- launch ----------------
extern "C" void kernel_launch(void* const* d_in, const int* in_sizes, int n_in,
                              void* d_out, int out_size, void* d_ws, size_t ws_size,
                              hipStream_t stream) {
  const float* x   = (const float*)d_in[0];
  const float* Wd1 = (const float*)d_in[1];
  const float* bd1 = (const float*)d_in[2];
  const float* Wd2 = (const float*)d_in[3];
  const float* bd2 = (const float*)d_in[4];
  const float* Wdo = (const float*)d_in[5];
  const float* bdo = (const float*)d_in[6];
  const float* Wo1 = (const float*)d_in[7];
  const float* bo1 = (const float*)d_in[8];
  const float* Wo2 = (const float*)d_in[9];
  const float* bo2 = (const float*)d_in[10];
  const float* Woo = (const float*)d_in[11];
  const float* boo = (const float*)d_in[12];
  float* out = (float*)d_out;

  char* ws = (char*)d_ws;
  // Wcat (bf16 elems): Wo1@0 | Wo2@16384 | Wd1@81920 | Wd2@98304 | Wdo@163840
  __bf16* Wcat = (__bf16*)(ws + 0);          //   360448 B
  __bf16* Woob = (__bf16*)(ws + 360448);     //  1048576 B (zero-padded rows)
  __bf16* g2   = (__bf16*)(ws + 1409024);    // 16777216 B
  float*  xdp  = (float*)(ws + 18186240);    //  8388608 B
  const size_t zoff = 26574848;
  __bf16* zq   = (__bf16*)(ws + zoff);       // z slice buffer [QSs][2048] bf16

  const size_t zcap = (ws_size > zoff) ? (ws_size - zoff) : 0;
  int nslices = 4;
  if (zcap >= (size_t)B_TOT * ZROWB) nslices = 1;
  else if (zcap >= (size_t)(B_TOT / 2) * ZROWB) nslices = 2;
  const int QSs = B_TOT / nslices;
  const int nbm = QSs / 128;       // 128-sample tiles
  const int bmper = nbm >> 3;

  cast_all_kernel<<<512, 256, 0, stream>>>(
      Wo1, Wcat, HDIM * NDIM,
      Wo2, Wcat + 16384, HDIM * HDIM,
      Wd1, Wcat + 81920, HDIM * NDIM,
      Wd2, Wcat + 98304, HDIM * HDIM,
      Wdo, Wcat + 163840, NDIM * HDIM,
      Woo, Woob, OFFD * HDIM,
      Woob + OFFD * HDIM, 32 * HDIM);

  (void)hipFuncSetAttribute((const void*)off_trunk_kernel,
                            hipFuncAttributeMaxDynamicSharedMemorySize, TRK_SMEM);
  (void)hipFuncSetAttribute((const void*)diag_trunk_kernel,
                            hipFuncAttributeMaxDynamicSharedMemorySize, TRK_SMEM);
  off_trunk_kernel<<<B_TOT / 64, 512, TRK_SMEM, stream>>>(
      x, Wcat, bo1, bo2, g2);
  diag_trunk_kernel<<<B_TOT / 64, 512, TRK_SMEM, stream>>>(
      x, Wcat + 81920, bd1, bd2, bdo, xdp);

  (void)hipFuncSetAttribute((const void*)gemm_z_kernel,
                            hipFuncAttributeMaxDynamicSharedMemorySize, GZ_SMEM);
  (void)hipFuncSetAttribute((const void*)apply_kernel,
                            hipFuncAttributeMaxDynamicSharedMemorySize, APPLY_SMEM);
  for (int s = 0; s < nslices; ++s) {
    gemm_z_kernel<<<nbm * 16, 256, GZ_SMEM, stream>>>(
        g2 + (size_t)s * QSs * HDIM, Woob, boo, zq, bmper);
    apply_kernel<<<QSs / 16, 512, APPLY_SMEM, stream>>>(zq, xdp, x, out, s * QSs);
  }
}

// Round 26
// 141.747 us; speedup vs baseline: 1.2373x; 1.0314x over previous
//
#include <hip/hip_runtime.h>
#include <math.h>

// Damping: B=32768, N=64, H=256, OFF=2016
//   diag: x -> tanh(Wd1) -> tanh(Wd2) -> Wdo   (64 per sample)
//   off : x -> tanh(Wo1) -> tanh(Wo2) -> Woo   (2016 per sample, strict lower tri)
//   out = L (L^T x0), L diag = xd, L[i][j](j<i) = z[i(i-1)/2+j]
//
// z path v7: gemm_z (128x128 tile, operand-swapped MFMA, LDS row-transpose
// epilogue -> NON-TEMPORAL full-line 16B stores) -> plain z[s][2048] -> apply.
// Trunks merged into ONE dispatch (off WGs 0..511, diag WGs 512..1023).

#define B_TOT 32768
#define NDIM  64
#define HDIM  256
#define OFFD  2016
#define ZCOLS 2048                 // padded row length (bf16)
#define ZROWB 4096                 // bytes per z row

typedef __bf16 bf16x8 __attribute__((ext_vector_type(8)));
typedef float  f32x4  __attribute__((ext_vector_type(4)));
typedef unsigned u32x4 __attribute__((ext_vector_type(4)));

__device__ __forceinline__ float fast_tanh(float x) {
  float e = __expf(2.f * x);
  return 1.f - 2.f * __builtin_amdgcn_rcpf(e + 1.f);
}
__device__ __forceinline__ float lane_bcast(float v, int l) {
  return __uint_as_float(__builtin_amdgcn_readlane(__float_as_uint(v), l));
}
__device__ __forceinline__ float bf_lo(unsigned w) { return __uint_as_float(w << 16); }
__device__ __forceinline__ float bf_hi(unsigned w) { return __uint_as_float(w & 0xffff0000u); }
__device__ __forceinline__ unsigned long long bfb64(float a, float b, float c, float d) {
  __bf16 ha = (__bf16)a, hb = (__bf16)b, hc = (__bf16)c, hd = (__bf16)d;
  return (unsigned long long)__builtin_bit_cast(unsigned short, ha) |
         ((unsigned long long)__builtin_bit_cast(unsigned short, hb) << 16) |
         ((unsigned long long)__builtin_bit_cast(unsigned short, hc) << 32) |
         ((unsigned long long)__builtin_bit_cast(unsigned short, hd) << 48);
}

__device__ __forceinline__ void gload_lds16(const void* g, void* l) {
  __builtin_amdgcn_global_load_lds(
      (const __attribute__((address_space(1))) unsigned*)g,
      (__attribute__((address_space(3))) unsigned*)l, 16, 0, 0);
}

#define MFMA(A, B, C) __builtin_amdgcn_mfma_f32_16x16x32_bf16((A), (B), (C), 0, 0, 0)
#define SB0() __builtin_amdgcn_sched_barrier(0)
// XOR-swizzled 16B-granule byte offset within a row (low 3 bits of granule)
#define GOFF(g, row) (((((g) & ~7) | (((g) & 7) ^ ((row) & 7)))) << 4)

// ---------------- weight cast (f32 -> bf16) + Woob pad zero-fill ----------------
__device__ __forceinline__ void cast_range(const float* __restrict__ s,
                                           __bf16* __restrict__ d, int n) {
  int i = blockIdx.x * blockDim.x + threadIdx.x;
  const int stride = gridDim.x * blockDim.x;
  for (; i < n; i += stride) d[i] = (__bf16)s[i];
}
__global__ __launch_bounds__(256) void cast_all_kernel(
    const float* s0, __bf16* d0, int n0, const float* s1, __bf16* d1, int n1,
    const float* s2, __bf16* d2, int n2, const float* s3, __bf16* d3, int n3,
    const float* s4, __bf16* d4, int n4, const float* s5, __bf16* d5, int n5,
    __bf16* d6, int n6) {
  cast_range(s0, d0, n0); cast_range(s1, d1, n1); cast_range(s2, d2, n2);
  cast_range(s3, d3, n3); cast_range(s4, d4, n4); cast_range(s5, d5, n5);
  int i = blockIdx.x * blockDim.x + threadIdx.x;
  const int stride = gridDim.x * blockDim.x;
  for (; i < n6; i += stride) d6[i] = (__bf16)0.f;
}

__device__ __forceinline__ bf16x8 cvt8(const float* __restrict__ p) {
  const float4 u = *(const float4*)p;
  const float4 v = *(const float4*)(p + 4);
  bf16x8 r;
  r[0] = (__bf16)u.x; r[1] = (__bf16)u.y; r[2] = (__bf16)u.z; r[3] = (__bf16)u.w;
  r[4] = (__bf16)v.x; r[5] = (__bf16)v.y; r[6] = (__bf16)v.z; r[7] = (__bf16)v.w;
  return r;
}

// ---------------- shared trunk machinery: 64 samples/WG, 72KB LDS, 2 WG/CU ------
#define TRK_SMEM (8192 + 32768 + 32768)

// stage one 16KB weight chunk; rows are 128B if c<2 else 512B
__device__ __forceinline__ void stage_chunk2(const char* wreg, char* wb,
                                             int c, int wave) {
  const char* base = wreg + (size_t)c * 16384;
  char* dst = wb + (c & 1) * 16384;
  const int lane = threadIdx.x & 63;
  const int s0 = wave * 64 + lane;
  const int s1 = s0 + 512;
  if (c < 2) {  // 128-byte rows (8 granules)
    const int r0 = s0 >> 3, q0 = (s0 & 7) ^ (r0 & 7);
    gload_lds16(base + r0 * 128 + (q0 << 4), dst + wave * 1024);
    const int r1 = s1 >> 3, q1 = (s1 & 7) ^ (r1 & 7);
    gload_lds16(base + r1 * 128 + (q1 << 4), dst + (wave + 8) * 1024);
  } else {      // 512-byte rows (32 granules)
    const int r0 = s0 >> 5, g0 = s0 & 31;
    const int q0 = (g0 & 24) | ((g0 & 7) ^ (r0 & 7));
    gload_lds16(base + r0 * 512 + (q0 << 4), dst + wave * 1024);
    const int r1 = s1 >> 5, g1 = s1 & 31;
    const int q1 = (g1 & 24) | ((g1 & 7) ^ (r1 & 7));
    gload_lds16(base + r1 * 512 + (q1 << 4), dst + (wave + 8) * 1024);
  }
}

// ---------------- off body: x -> tanh(Wo1) -> tanh(Wo2) -> g2 -------------------
__device__ __forceinline__ void off_trunk_body(
    char* smem, int sb, const float* __restrict__ x,
    const __bf16* __restrict__ Wreg, const float* __restrict__ bo1,
    const float* __restrict__ bo2, __bf16* __restrict__ g2) {
  char* xa  = smem;            // 8 KB
  char* act = smem + 8192;     // 32 KB (g1)
  char* wb  = smem + 40960;    // 32 KB
  const char* Wc = (const char*)Wreg;

  const int tid = threadIdx.x;
  const int wave = tid >> 6, lane = tid & 63;
  const int lr = lane & 15, lg = lane >> 4;

  float bv1[2], bv2[8];
#pragma unroll
  for (int cc = 0; cc < 2; ++cc) bv1[cc] = bo1[cc * 128 + wave * 16 + lr];
#pragma unroll
  for (int cc = 0; cc < 8; ++cc) bv2[cc] = bo2[cc * 32 + (wave & 1) * 16 + lr];

  {
    const int s = tid >> 3, g = tid & 7;
    const bf16x8 v = cvt8(x + (size_t)(sb + s) * 64 + g * 8);
    *(bf16x8*)(xa + s * 128 + GOFF(g, s)) = v;
  }
  stage_chunk2(Wc, wb, 0, wave);
  __syncthreads();

#pragma unroll
  for (int cc = 0; cc < 2; ++cc) {
    stage_chunk2(Wc, wb, cc + 1, wave);
    const char* wbp = wb + (cc & 1) * 16384;
    const int brow = wave * 16 + lr;
    const bf16x8 b0 = *(const bf16x8*)(wbp + brow * 128 + GOFF(lg, brow));
    const bf16x8 b1 = *(const bf16x8*)(wbp + brow * 128 + GOFF(4 + lg, brow));
    const int ch = cc * 128 + brow;
#pragma unroll
    for (int m = 0; m < 4; ++m) {
      const int arow = m * 16 + lr;
      const bf16x8 a0 = *(const bf16x8*)(xa + arow * 128 + GOFF(lg, arow));
      const bf16x8 a1 = *(const bf16x8*)(xa + arow * 128 + GOFF(4 + lg, arow));
      f32x4 acc = {0.f, 0.f, 0.f, 0.f};
      acc = MFMA(a0, b0, acc);
      acc = MFMA(a1, b1, acc);
#pragma unroll
      for (int r = 0; r < 4; ++r) {
        const int s = m * 16 + lg * 4 + r;
        *(__bf16*)(act + s * 512 + GOFF(ch >> 3, s) + (ch & 7) * 2) =
            (__bf16)fast_tanh(acc[r] + bv1[cc]);
      }
    }
    __syncthreads();
  }

#pragma unroll
  for (int cc = 0; cc < 8; ++cc) {
    const int c = cc + 2;
    if (c + 1 < 10) stage_chunk2(Wc, wb, c + 1, wave);
    const char* wbp = wb + (c & 1) * 16384;
    const int m = wave >> 1, n = wave & 1;
    const int ch = cc * 32 + n * 16 + lr;
    const int brow = n * 16 + lr;
    const int arow = m * 16 + lr;
    f32x4 acc = {0.f, 0.f, 0.f, 0.f};
#pragma unroll
    for (int ks = 0; ks < 8; ++ks) {
      const int g = ks * 4 + lg;
      const bf16x8 a = *(const bf16x8*)(act + arow * 512 + GOFF(g, arow));
      const bf16x8 b = *(const bf16x8*)(wbp + brow * 512 + GOFF(g, brow));
      acc = MFMA(a, b, acc);
    }
#pragma unroll
    for (int r = 0; r < 4; ++r) {
      const int s = m * 16 + lg * 4 + r;
      g2[(size_t)(sb + s) * 256 + ch] = (__bf16)fast_tanh(acc[r] + bv2[cc]);
    }
    if (cc < 7) __syncthreads();
  }
}

// ---------------- diag body: x -> tanh(Wd1) -> tanh(Wd2) -> Wdo -> xd -----------
__device__ __forceinline__ void diag_trunk_body(
    char* smem, int sb, const float* __restrict__ x,
    const __bf16* __restrict__ Wreg, const float* __restrict__ bd1,
    const float* __restrict__ bd2, const float* __restrict__ bdo,
    float* __restrict__ xd) {
  char* xa  = smem;            // 8 KB
  char* act = smem + 8192;     // 32 KB (h1, then h2)
  char* wb  = smem + 40960;    // 32 KB
  const char* Wc = (const char*)Wreg;

  const int tid = threadIdx.x;
  const int wave = tid >> 6, lane = tid & 63;
  const int lr = lane & 15, lg = lane >> 4;

  float bv1[2], bv2[8], bv3[2];
#pragma unroll
  for (int cc = 0; cc < 2; ++cc) bv1[cc] = bd1[cc * 128 + wave * 16 + lr];
#pragma unroll
  for (int cc = 0; cc < 8; ++cc) bv2[cc] = bd2[cc * 32 + (wave & 1) * 16 + lr];
#pragma unroll
  for (int cc = 0; cc < 2; ++cc) bv3[cc] = bdo[cc * 32 + (wave & 1) * 16 + lr];

  {
    const int s = tid >> 3, g = tid & 7;
    const bf16x8 v = cvt8(x + (size_t)(sb + s) * 64 + g * 8);
    *(bf16x8*)(xa + s * 128 + GOFF(g, s)) = v;
  }
  stage_chunk2(Wc, wb, 0, wave);
  __syncthreads();

#pragma unroll
  for (int cc = 0; cc < 2; ++cc) {
    stage_chunk2(Wc, wb, cc + 1, wave);
    const char* wbp = wb + (cc & 1) * 16384;
    const int brow = wave * 16 + lr;
    const bf16x8 b0 = *(const bf16x8*)(wbp + brow * 128 + GOFF(lg, brow));
    const bf16x8 b1 = *(const bf16x8*)(wbp + brow * 128 + GOFF(4 + lg, brow));
    const int ch = cc * 128 + brow;
#pragma unroll
    for (int m = 0; m < 4; ++m) {
      const int arow = m * 16 + lr;
      const bf16x8 a0 = *(const bf16x8*)(xa + arow * 128 + GOFF(lg, arow));
      const bf16x8 a1 = *(const bf16x8*)(xa + arow * 128 + GOFF(4 + lg, arow));
      f32x4 acc = {0.f, 0.f, 0.f, 0.f};
      acc = MFMA(a0, b0, acc);
      acc = MFMA(a1, b1, acc);
#pragma unroll
      for (int r = 0; r < 4; ++r) {
        const int s = m * 16 + lg * 4 + r;
        *(__bf16*)(act + s * 512 + GOFF(ch >> 3, s) + (ch & 7) * 2) =
            (__bf16)fast_tanh(acc[r] + bv1[cc]);
      }
    }
    __syncthreads();
  }

  f32x4 h2v[8];
#pragma unroll
  for (int cc = 0; cc < 8; ++cc) {
    const int c = cc + 2;
    if (c + 1 < 11) stage_chunk2(Wc, wb, c + 1, wave);
    const char* wbp = wb + (c & 1) * 16384;
    const int m = wave >> 1, n = wave & 1;
    const int brow = n * 16 + lr;
    const int arow = m * 16 + lr;
    f32x4 acc = {0.f, 0.f, 0.f, 0.f};
#pragma unroll
    for (int ks = 0; ks < 8; ++ks) {
      const int g = ks * 4 + lg;
      const bf16x8 a = *(const bf16x8*)(act + arow * 512 + GOFF(g, arow));
      const bf16x8 b = *(const bf16x8*)(wbp + brow * 512 + GOFF(g, brow));
      acc = MFMA(a, b, acc);
    }
#pragma unroll
    for (int r = 0; r < 4; ++r) h2v[cc][r] = fast_tanh(acc[r] + bv2[cc]);
    __syncthreads();
  }

  {
    const int m = wave >> 1, n = wave & 1;
#pragma unroll
    for (int cc = 0; cc < 8; ++cc) {
      const int ch = cc * 32 + n * 16 + lr;
#pragma unroll
      for (int r = 0; r < 4; ++r) {
        const int s = m * 16 + lg * 4 + r;
        *(__bf16*)(act + s * 512 + GOFF(ch >> 3, s) + (ch & 7) * 2) =
            (__bf16)h2v[cc][r];
      }
    }
  }
  stage_chunk2(Wc, wb, 11, wave);
  __syncthreads();

#pragma unroll
  for (int cc = 0; cc < 2; ++cc) {
    const char* wbp = wb + ((10 + cc) & 1) * 16384;
    const int m = wave >> 1, n = wave & 1;
    const int ch = cc * 32 + n * 16 + lr;
    const int brow = n * 16 + lr;
    const int arow = m * 16 + lr;
    f32x4 acc = {0.f, 0.f, 0.f, 0.f};
#pragma unroll
    for (int ks = 0; ks < 8; ++ks) {
      const int g = ks * 4 + lg;
      const bf16x8 a = *(const bf16x8*)(act + arow * 512 + GOFF(g, arow));
      const bf16x8 b = *(const bf16x8*)(wbp + brow * 512 + GOFF(g, brow));
      acc = MFMA(a, b, acc);
    }
#pragma unroll
    for (int r = 0; r < 4; ++r) {
      const int s = m * 16 + lg * 4 + r;
      xd[(size_t)(sb + s) * 64 + ch] = acc[r] + bv3[cc];
    }
  }
}

// ---------------- trunk_dual: one dispatch, off (0..noff-1) + diag (rest) -------
__global__ __launch_bounds__(512, 2) void trunk_dual_kernel(
    const float* __restrict__ x, const __bf16* __restrict__ Wcat,
    const float* __restrict__ bo1, const float* __restrict__ bo2,
    const float* __restrict__ bd1, const float* __restrict__ bd2,
    const float* __restrict__ bdo,
    __bf16* __restrict__ g2, float* __restrict__ xd, int noff) {
  extern __shared__ char smem[];
  const int bid = blockIdx.x;
  if (bid < noff) {
    off_trunk_body(smem, bid * 64, x, Wcat, bo1, bo2, g2);
  } else {
    diag_trunk_body(smem, (bid - noff) * 64, x, Wcat + 81920, bd1, bd2, bdo, xd);
  }
}

// ---------------- gemm_z v7: operand-swapped 128x128 tile, 4 WG/CU --------------
// A-operand = Woob rows (z cols), B-operand = g2 rows (samples).
// Epilogue: acc -> LDS T[128 smp][32 u64 slots] (swizzled), then NON-TEMPORAL
// 16B stores (streaming z bypasses L2 -> no write-allocate / eviction churn).
#define GZ_SMEM 32768

__global__ __launch_bounds__(256, 4) void gemm_z_kernel(
    const __bf16* __restrict__ g2q, const __bf16* __restrict__ Woob,
    const float* __restrict__ boo, __bf16* __restrict__ zq, int bmper) {
  extern __shared__ char gsm[];
  const int tid = threadIdx.x;
  const int wave = tid >> 6, lane = tid & 63;
  const int lr = lane & 15, lg = lane >> 4;
  // XCD owns a contiguous bm range (g2 slice + Woob stay L2-resident)
  const int bm = (blockIdx.x & 7) * bmper + (blockIdx.x >> 7);
  const int bn = (blockIdx.x >> 3) & 15;
  const int wr = wave >> 1;      // woo-col half (64 cols)
  const int wc = wave & 1;       // sample half (64 samples)
  const int srl = lane >> 3, sch = lane & 7;

#define GZSTAGE(KT)                                                             \
  {                                                                             \
    _Pragma("unroll")                                                           \
    for (int j = 0; j < 4; ++j) {                                               \
      const int row = wave * 32 + j * 8 + srl;                                  \
      const int ka = (KT) * 64 + ((sch ^ (row & 7)) << 3);                      \
      gload_lds16(g2q + (size_t)(bm * 128 + row) * 256 + ka,                    \
                  gsm + wave * 4096 + j * 1024);                                \
      gload_lds16(Woob + (size_t)(bn * 128 + row) * 256 + ka,                   \
                  gsm + 16384 + wave * 4096 + j * 1024);                        \
    }                                                                           \
  }

  // bias per (fr, r): z col = bn*128 + wr*64 + fr*16 + lg*4 + r
  float bvf[4][4];
#pragma unroll
  for (int fr = 0; fr < 4; ++fr)
#pragma unroll
    for (int r = 0; r < 4; ++r) {
      const int col = bn * 128 + wr * 64 + fr * 16 + lg * 4 + r;
      bvf[fr][r] = (col < OFFD) ? boo[col] : 0.f;
    }

  f32x4 acc[4][4];
#pragma unroll
  for (int i = 0; i < 4; ++i)
#pragma unroll
    for (int j = 0; j < 4; ++j) acc[i][j] = (f32x4){0.f, 0.f, 0.f, 0.f};

  GZSTAGE(0)
  __syncthreads();

#pragma unroll
  for (int kt = 0; kt < 4; ++kt) {
    if (kt > 0) {
      GZSTAGE(kt)
      __syncthreads();
    }
    const char* Gb = gsm;            // g2 tile (samples)
    const char* Wb = gsm + 16384;    // Woob tile (z cols)
#pragma unroll
    for (int ks = 0; ks < 2; ++ks) {
      bf16x8 af[4], bfr[4];
#pragma unroll
      for (int f = 0; f < 4; ++f) {
        const int ra = wr * 64 + f * 16 + lr;            // woo-col rows (A)
        af[f] = *(const bf16x8*)(Wb + ra * 128 + GOFF(ks * 4 + lg, ra));
        const int rb = wc * 64 + f * 16 + lr;            // sample rows (B)
        bfr[f] = *(const bf16x8*)(Gb + rb * 128 + GOFF(ks * 4 + lg, rb));
      }
#pragma unroll
      for (int fr = 0; fr < 4; ++fr)
#pragma unroll
        for (int fc = 0; fc < 4; ++fc)
          acc[fr][fc] = MFMA(af[fr], bfr[fc], acc[fr][fc]);
    }
    __syncthreads();   // last iteration: staging reads certified before T reuse
  }

  // ---- epilogue: acc -> LDS T (row-major per sample), then NT 16B stores ----
  {
    unsigned long long* Tq = (unsigned long long*)gsm;  // [128 rows][32 slots]
#pragma unroll
    for (int fc = 0; fc < 4; ++fc) {
      const int smp_l = wc * 64 + fc * 16 + lr;        // local sample row
#pragma unroll
      for (int fr = 0; fr < 4; ++fr) {
        const int s = wr * 16 + fr * 4 + lg;           // u64 slot (4 cols)
        const int sw = (s & ~7) | ((s & 7) ^ (smp_l & 7));
        Tq[smp_l * 32 + sw] =
            bfb64(acc[fr][fc][0] + bvf[fr][0], acc[fr][fc][1] + bvf[fr][1],
                  acc[fr][fc][2] + bvf[fr][2], acc[fr][fc][3] + bvf[fr][3]);
      }
    }
  }
  __syncthreads();

  {
    const unsigned long long* Tq = (const unsigned long long*)gsm;
#pragma unroll
    for (int it = 0; it < 8; ++it) {
      const int gi = tid + it * 256;     // 16B granule 0..2047
      const int row = gi >> 4;           // local sample row
      const int gcol = gi & 15;          // 16B granule within row
      const int s0 = gcol * 2, s1 = s0 + 1;
      const unsigned long long a =
          Tq[row * 32 + ((s0 & ~7) | ((s0 & 7) ^ (row & 7)))];
      const unsigned long long b =
          Tq[row * 32 + ((s1 & ~7) | ((s1 & 7) ^ (row & 7)))];
      u32x4 w;
      w.x = (unsigned)a; w.y = (unsigned)(a >> 32);
      w.z = (unsigned)b; w.w = (unsigned)(b >> 32);
      const int smp = bm * 128 + row;
      __builtin_nontemporal_store(
          w, (u32x4*)(zq + (size_t)smp * ZCOLS + bn * 128 + gcol * 8));
    }
  }
}

// ---------------- apply v4: 512 thr, 16 samples, plain-row stage, 2 WG/CU -------
// LDS: zs 16 x 4096B = 64KB | ys 8 x 128 f32 = 4KB
#define APPLY_SMEM (65536 + 4096)
__global__ __launch_bounds__(512, 2) void apply_kernel(
    const __bf16* __restrict__ zq, const float* __restrict__ xd,
    const float* __restrict__ x0, float* __restrict__ out, int s0base) {
  extern __shared__ char smem[];
  float* ys2 = (float*)(smem + 65536);

  const int tid = threadIdx.x;
  const int wave = tid >> 6, lane = tid & 63;
  const int sb = s0base + blockIdx.x * 16;
  const int s0 = wave * 2, s1 = s0 + 1;

  const float x0vA = x0[(size_t)(sb + s0) * 64 + lane];
  const float x0vB = x0[(size_t)(sb + s1) * 64 + lane];
  const float xdA = xd[(size_t)(sb + s0) * 64 + lane];
  const float xdB = xd[(size_t)(sb + s1) * 64 + lane];

  // linear stage: 2 sample rows (4096 B each) per wave
  {
    const char* srcA = (const char*)(zq + (size_t)(sb + s0) * ZCOLS);
    char* dstA = smem + wave * 8192;
#pragma unroll
    for (int j = 0; j < 4; ++j) {
      gload_lds16(srcA + j * 1024 + lane * 16, dstA + j * 1024);
      gload_lds16(srcA + ZROWB + j * 1024 + lane * 16, dstA + 4096 + j * 1024);
    }
  }
  asm volatile("s_waitcnt vmcnt(0)" ::: "memory");
  SB0();

  const __bf16* zsA = (const __bf16*)(smem + wave * 8192);
  const __bf16* zsB = zsA + ZCOLS;

  // pass 1: y_j = xd_j x0_j + sum_{k>j} z[k(k-1)/2 + j] x0_k   (j = lane)
  float yA = xdA * x0vA, yB = xdB * x0vB;
  int rs = 0;
#pragma unroll
  for (int k = 1; k < 64; ++k) {
    const float zA = (float)zsA[rs + lane];
    const float zB = (float)zsB[rs + lane];
    const float xkA = lane_bcast(x0vA, k);
    const float xkB = lane_bcast(x0vB, k);
    const bool mv = lane < k;
    yA += mv ? zA * xkA : 0.f;
    yB += mv ? zB * xkB : 0.f;
    rs += k;
  }

  float* ypA = ys2 + wave * 128;
  float* ypB = ypA + 64;
  ypA[lane] = yA;
  ypB[lane] = yB;
  asm volatile("s_waitcnt lgkmcnt(0)" ::: "memory");
  SB0();

  // pass 2: D_i = xd_i y_i + sum_{j<i} z[i(i-1)/2 + j] y_j   (i = lane)
  float DA = xdA * yA, DB = xdB * yB;
  {
    const int base = (lane * (lane - 1)) >> 1;
    const int nf = lane >> 3;
    const int t = lane & 7;
    const char* zrA = (const char*)zsA + base * 2;
    const char* zrB = (const char*)zsB + base * 2;
    for (int c = 0; c < nf; ++c) {
      const uint4 wA = *(const uint4*)(zrA + c * 16);
      const uint4 wB = *(const uint4*)(zrB + c * 16);
      const float4 u0 = *(const float4*)(ypA + c * 8);
      const float4 u1 = *(const float4*)(ypA + c * 8 + 4);
      const float4 v0 = *(const float4*)(ypB + c * 8);
      const float4 v1 = *(const float4*)(ypB + c * 8 + 4);
      DA += bf_lo(wA.x) * u0.x + bf_hi(wA.x) * u0.y + bf_lo(wA.y) * u0.z +
            bf_hi(wA.y) * u0.w + bf_lo(wA.z) * u1.x + bf_hi(wA.z) * u1.y +
            bf_lo(wA.w) * u1.z + bf_hi(wA.w) * u1.w;
      DB += bf_lo(wB.x) * v0.x + bf_hi(wB.x) * v0.y + bf_lo(wB.y) * v0.z +
            bf_hi(wB.y) * v0.w + bf_lo(wB.z) * v1.x + bf_hi(wB.z) * v1.y +
            bf_lo(wB.w) * v1.z + bf_hi(wB.w) * v1.w;
    }
    if (t) {
      const uint4 wA = *(const uint4*)(zrA + nf * 16);
      const uint4 wB = *(const uint4*)(zrB + nf * 16);
      const float4 u0 = *(const float4*)(ypA + nf * 8);
      const float4 u1 = *(const float4*)(ypA + nf * 8 + 4);
      const float4 v0 = *(const float4*)(ypB + nf * 8);
      const float4 v1 = *(const float4*)(ypB + nf * 8 + 4);
      DA += ((0 < t) ? bf_lo(wA.x) * u0.x : 0.f) + ((1 < t) ? bf_hi(wA.x) * u0.y : 0.f) +
            ((2 < t) ? bf_lo(wA.y) * u0.z : 0.f) + ((3 < t) ? bf_hi(wA.y) * u0.w : 0.f) +
            ((4 < t) ? bf_lo(wA.z) * u1.x : 0.f) + ((5 < t) ? bf_hi(wA.z) * u1.y : 0.f) +
            ((6 < t) ? bf_lo(wA.w) * u1.z : 0.f);
      DB += ((0 < t) ? bf_lo(wB.x) * v0.x : 0.f) + ((1 < t) ? bf_hi(wB.x) * v0.y : 0.f) +
            ((2 < t) ? bf_lo(wB.y) * v0.z : 0.f) + ((3 < t) ? bf_hi(wB.y) * v0.w : 0.f) +
            ((4 < t) ? bf_lo(wB.z) * v1.x : 0.f) + ((5 < t) ? bf_hi(wB.z) * v1.y : 0.f) +
            ((6 < t) ? bf_lo(wB.w) * v1.z : 0.f);
    }
  }
  __builtin_nontemporal_store(DA, out + (size_t)(sb + s0) * 64 + lane);
  __builtin_nontemporal_store(DB, out + (size_t)(sb + s1) * 64 + lane);
}

// ---------------- launch ----------------
extern "C" void kernel_launch(void* const* d_in, const int* in_sizes, int n_in,
                              void* d_out, int out_size, void* d_ws, size_t ws_size,
                              hipStream_t stream) {
  const float* x   = (const float*)d_in[0];
  const float* Wd1 = (const float*)d_in[1];
  const float* bd1 = (const float*)d_in[2];
  const float* Wd2 = (const float*)d_in[3];
  const float* bd2 = (const float*)d_in[4];
  const float* Wdo = (const float*)d_in[5];
  const float* bdo = (const float*)d_in[6];
  const float* Wo1 = (const float*)d_in[7];
  const float* bo1 = (const float*)d_in[8];
  const float* Wo2 = (const float*)d_in[9];
  const float* bo2 = (const float*)d_in[10];
  const float* Woo = (const float*)d_in[11];
  const float* boo = (const float*)d_in[12];
  float* out = (float*)d_out;

  char* ws = (char*)d_ws;
  // Wcat (bf16 elems): Wo1@0 | Wo2@16384 | Wd1@81920 | Wd2@98304 | Wdo@163840
  __bf16* Wcat = (__bf16*)(ws + 0);          //   360448 B
  __bf16* Woob = (__bf16*)(ws + 360448);     //  1048576 B (zero-padded rows)
  __bf16* g2   = (__bf16*)(ws + 1409024);    // 16777216 B
  float*  xdp  = (float*)(ws + 18186240);    //  8388608 B
  const size_t zoff = 26574848;
  __bf16* zq   = (__bf16*)(ws + zoff);       // z slice buffer [QSs][2048] bf16

  const size_t zcap = (ws_size > zoff) ? (ws_size - zoff) : 0;
  int nslices = 4;
  if (zcap >= (size_t)B_TOT * ZROWB) nslices = 1;
  else if (zcap >= (size_t)(B_TOT / 2) * ZROWB) nslices = 2;
  const int QSs = B_TOT / nslices;
  const int nbm = QSs / 128;       // 128-sample tiles
  const int bmper = nbm >> 3;

  cast_all_kernel<<<512, 256, 0, stream>>>(
      Wo1, Wcat, HDIM * NDIM,
      Wo2, Wcat + 16384, HDIM * HDIM,
      Wd1, Wcat + 81920, HDIM * NDIM,
      Wd2, Wcat + 98304, HDIM * HDIM,
      Wdo, Wcat + 163840, NDIM * HDIM,
      Woo, Woob, OFFD * HDIM,
      Woob + OFFD * HDIM, 32 * HDIM);

  (void)hipFuncSetAttribute((const void*)trunk_dual_kernel,
                            hipFuncAttributeMaxDynamicSharedMemorySize, TRK_SMEM);
  trunk_dual_kernel<<<B_TOT / 64 * 2, 512, TRK_SMEM, stream>>>(
      x, Wcat, bo1, bo2, bd1, bd2, bdo, g2, xdp, B_TOT / 64);

  (void)hipFuncSetAttribute((const void*)gemm_z_kernel,
                            hipFuncAttributeMaxDynamicSharedMemorySize, GZ_SMEM);
  (void)hipFuncSetAttribute((const void*)apply_kernel,
                            hipFuncAttributeMaxDynamicSharedMemorySize, APPLY_SMEM);
  for (int s = 0; s < nslices; ++s) {
    gemm_z_kernel<<<nbm * 16, 256, GZ_SMEM, stream>>>(
        g2 + (size_t)s * QSs * HDIM, Woob, boo, zq, bmper);
    apply_kernel<<<QSs / 16, 512, APPLY_SMEM, stream>>>(zq, xdp, x, out, s * QSs);
  }
}